// Round 7
// baseline (365.470 us; speedup 1.0000x reference)
//
#include <hip/hip_runtime.h>

// SSIM over 11x11 gaussian-weighted patches.
// pred: [4, 2048, 16, 121, 3] f32   gt: [2048, 16, 121, 3] f32
// out:  [4, 2048, 16] f32
//
// R7: R6 skeleton (wave-private pred staging, no __syncthreads) with the
// instruction-count cuts the R6 counters demanded:
//  - pixel-PAIR compute reads (6 floats): ds_read2_b32-fusable offset pairs
//    (0/3, 1/4, 2/5) -> 4 rounds, ~12 DS reads vs 24 scalar.
//  - reduction via LDS transpose-reduce OVERLAID on the wave's own staging
//    slice (consumed by then; same-wave DS ops are in-order): 4 ds_write_b128
//    + 16 ds_read_b32 + 1 write + 4 reads ~= 25 DS vs 60 ds_swizzle shuffles.
//  - __launch_bounds__(256,6): 23.3 KB LDS -> up to 6 blocks/CU.
// gt pixel-B loads guarded at pair 60 (gt buffer end is page-aligned; no
// over-read). Pred staging is exactly 363 float4/wave (no over-read).

static constexpr int N_OUT   = 4 * 2048 * 16;   // 131072
static constexpr int NP_MASK = 2048 * 16 - 1;   // 32767 (N*n_p is pow2)
static constexpr int OPB     = 16;              // outputs per block
static constexpr int V4_WAVE = 363;             // float4 per wave slice
static constexpr int LDS_F4  = 4 * V4_WAVE + 2; // +8 floats pad for pair-60 reads

__device__ __constant__ float G11[11] = {
    0.00102838f, 0.00759875f, 0.03600077f, 0.10936070f, 0.21300555f,
    0.26601173f,
    0.21300555f, 0.10936070f, 0.03600077f, 0.00759875f, 0.00102838f
};

__global__ __launch_bounds__(256, 6) void ssim_kernel(
    const float* __restrict__ pred, const float* __restrict__ gt,
    float* __restrict__ out)
{
    __shared__ float4 predS4[LDS_F4];   // 23,264 B

    const int t      = threadIdx.x;
    const int wave   = t >> 6;
    const int lane64 = t & 63;
    const int lane   = t & 15;          // lane within 16-lane group
    const int group  = t >> 4;          // 0..15 (== wave*4 + q)
    const int o      = blockIdx.x * OPB + group;

    // ---- gt -> registers first (L2/L3-resident; latency overlaps staging)
    const float* g = gt + (size_t)(o & NP_MASK) * 363;
    float gv[4][6];
    #pragma unroll
    for (int r = 0; r < 4; ++r) {
        const int k  = lane + r * 16;           // pair index 0..63
        const int kc = (k < 60 ? k : 60);       // clamp (w=0 past 60)
        const float* gk = g + 6 * kc;
        gv[r][0] = gk[0]; gv[r][1] = gk[1]; gv[r][2] = gk[2];
        const bool full = (k < 60);             // pair 60 = pixel 120 only;
        gv[r][3] = full ? gk[3] : 0.f;          // gt end is page-aligned ->
        gv[r][4] = full ? gk[4] : 0.f;          // must not over-read
        gv[r][5] = full ? gk[5] : 0.f;
    }

    // ---- wave-private pred staging: exactly 363 float4, no barrier ----
    const float4* p4 = (const float4*)(pred +
                        (size_t)(blockIdx.x * OPB + wave * 4) * 363);
    #pragma unroll
    for (int r = 0; r < 6; ++r) {
        const int idx = lane64 + r * 64;
        if (idx < V4_WAVE) predS4[wave * V4_WAVE + idx] = p4[idx];
    }

    // ---- per-pair gaussian weights (registers; compiler magic-divs /11)
    float wA[4], wB[4];
    #pragma unroll
    for (int r = 0; r < 4; ++r) {
        const int k  = lane + r * 16;
        const int pa = 2 * k, pb = 2 * k + 1;
        wA[r] = (pa <= 120) ? G11[pa / 11] * G11[pa % 11] : 0.f;
        wB[r] = (pb <= 120) ? G11[pb / 11] * G11[pb % 11] : 0.f;
    }

    asm volatile("s_waitcnt lgkmcnt(0)" ::: "memory");  // our LDS writes done

    // ---- compute: pixel-pair per lane per round, pred from LDS ----
    const float* P = (const float*)predS4 + group * 363;
    float mu1[3] = {0.f, 0.f, 0.f};
    float mu2[3] = {0.f, 0.f, 0.f};
    float sp [3] = {0.f, 0.f, 0.f};
    float sg [3] = {0.f, 0.f, 0.f};
    float spg[3] = {0.f, 0.f, 0.f};

    #pragma unroll
    for (int r = 0; r < 4; ++r) {
        const int k  = lane + r * 16;
        const int kc = (k < 60 ? k : 60);
        const float* Pk = P + 6 * kc;
        // ds_read2_b32-fusable pairs: {0,3}, {1,4}, {2,5}
        const float pA[3] = {Pk[0], Pk[1], Pk[2]};
        const float pB[3] = {Pk[3], Pk[4], Pk[5]};
        #pragma unroll
        for (int c = 0; c < 3; ++c) {
            const float ga = gv[r][c], gb = gv[r][c + 3];
            float tp = wA[r] * pA[c];
            float tg = wA[r] * ga;
            mu1[c] += tp;  mu2[c] += tg;
            sp [c] = fmaf(tp, pA[c], sp [c]);
            sg [c] = fmaf(tg, ga,    sg [c]);
            spg[c] = fmaf(tp, ga,    spg[c]);
            float up = wB[r] * pB[c];
            float ug = wB[r] * gb;
            mu1[c] += up;  mu2[c] += ug;
            sp [c] = fmaf(up, pB[c], sp [c]);
            sg [c] = fmaf(ug, gb,    sg [c]);
            spg[c] = fmaf(up, gb,    spg[c]);
        }
    }

    // ---- LDS transpose-reduce, overlaid on this wave's consumed slice ----
    float* scr = (float*)predS4 + wave * 1452;   // 16-B aligned (1452*4 % 16 == 0)
    {
        const int q = lane64 >> 4;               // output within wave (0..3)
        const int j = lane;                      // contributor (0..15)
        float4* dst = (float4*)(scr + (j * 4 + q) * 20);  // 80-B slots
        dst[0] = make_float4(mu1[0], mu1[1], mu1[2], mu2[0]);
        dst[1] = make_float4(mu2[1], mu2[2], sp[0], sp[1]);
        dst[2] = make_float4(sp[2],  sg[0],  sg[1], sg[2]);
        dst[3] = make_float4(spg[0], spg[1], spg[2], 0.f);
    }
    asm volatile("s_waitcnt lgkmcnt(0)" ::: "memory");

    const int q2 = lane64 >> 4;                  // output (0..3)
    const int st = lane64 & 15;                  // stat (0..14 active)
    if (st < 15) {
        float sum = 0.f;
        #pragma unroll
        for (int j2 = 0; j2 < 16; ++j2)
            sum += scr[(j2 * 4 + q2) * 20 + st];
        scr[q2 * 16 + st] = sum;                 // gather region, disjoint
    }
    asm volatile("s_waitcnt lgkmcnt(0)" ::: "memory");

    // ---- epilogue: lanes 0..3 finish one output each ----
    if (lane64 < 4) {
        const float4* sv = (const float4*)(scr + lane64 * 16);
        const float4 a = sv[0], b = sv[1], c4 = sv[2], d = sv[3];
        const float M1[3]  = {a.x,  a.y,  a.z};
        const float M2[3]  = {a.w,  b.x,  b.y};
        const float S1[3]  = {b.z,  b.w,  c4.x};
        const float S2[3]  = {c4.y, c4.z, c4.w};
        const float S12[3] = {d.x,  d.y,  d.z};
        const float C1 = 1e-4f;   // 0.01^2
        const float C2 = 9e-4f;   // 0.03^2
        float acc = 0.f;
        #pragma unroll
        for (int c = 0; c < 3; ++c) {
            const float m1 = M1[c], m2 = M2[c];
            const float m1sq = m1 * m1, m2sq = m2 * m2, m12 = m1 * m2;
            const float sig1 = S1[c]  - m1sq;
            const float sig2 = S2[c]  - m2sq;
            const float sg12 = S12[c] - m12;
            const float num = (2.f * m12 + C1) * (2.f * sg12 + C2);
            const float den = (m1sq + m2sq + C1) * (sig1 + sig2 + C2);
            acc += num / den;
        }
        out[blockIdx.x * OPB + wave * 4 + lane64] = acc * (1.f / 3.f);
    }
}

extern "C" void kernel_launch(void* const* d_in, const int* in_sizes, int n_in,
                              void* d_out, int out_size, void* d_ws, size_t ws_size,
                              hipStream_t stream) {
    const float* pred = (const float*)d_in[0];
    const float* gt   = (const float*)d_in[1];
    float* out        = (float*)d_out;
    ssim_kernel<<<N_OUT / OPB, 256, 0, stream>>>(pred, gt, out);  // 8192 blocks
}